// Round 1
// baseline (408.157 us; speedup 1.0000x reference)
//
#include <hip/hip_runtime.h>
#include <stdint.h>

typedef __bf16 bf16x8 __attribute__((ext_vector_type(8)));
typedef float  f32x4  __attribute__((ext_vector_type(8/2)));  // 4 floats

__device__ __forceinline__ unsigned short f2bf(float f) {
    union { float f; unsigned int u; } v; v.f = f;
    unsigned int u = v.u;
    // round-to-nearest-even bf16
    return (unsigned short)((u + 0x7FFFu + ((u >> 16) & 1u)) >> 16);
}

// ---------------------------------------------------------------------------
// Kernel 1: cast x (fp32) -> bf16 A[M][K]. Pure bandwidth.
// ---------------------------------------------------------------------------
__global__ void cast_x_kernel(const float4* __restrict__ X,
                              ushort4* __restrict__ A, int n4) {
    int i = blockIdx.x * blockDim.x + threadIdx.x;
    if (i < n4) {
        float4 v = X[i];
        ushort4 o;
        o.x = f2bf(v.x); o.y = f2bf(v.y); o.z = f2bf(v.z); o.w = f2bf(v.w);
        A[i] = o;
    }
}

// ---------------------------------------------------------------------------
// Kernel 2: FWHT each row of W (len 2048), scale 1/sqrt(2048), emit bf16.
// H is symmetric+orthogonal: (xH/vn) W^T == x (W H /vn)^T, so transforming
// W's 2048 rows replaces transforming x's 16384 rows.
// ---------------------------------------------------------------------------
__global__ void fwht_w_kernel(const float* __restrict__ W,
                              unsigned short* __restrict__ Bt) {
    const int n = 2048;
    __shared__ float buf[2048];
    const float* src = W + (size_t)blockIdx.x * n;
    for (int i = threadIdx.x; i < n; i += 256) buf[i] = src[i];
    __syncthreads();
    for (int len = 1; len < n; len <<= 1) {
        for (int j = threadIdx.x; j < n / 2; j += 256) {
            int idx = ((j & ~(len - 1)) << 1) | (j & (len - 1));
            float a = buf[idx], b = buf[idx + len];
            buf[idx]       = a + b;
            buf[idx + len] = a - b;
        }
        __syncthreads();
    }
    const float scale = 0.02209708691207961f; // 1/sqrt(2048)
    unsigned short* dst = Bt + (size_t)blockIdx.x * n;
    for (int i = threadIdx.x; i < n; i += 256) dst[i] = f2bf(buf[i] * scale);
}

// ---------------------------------------------------------------------------
// Kernel 3: C[M][N] = A[M][K] * B[N][K]^T + bias, bf16 MFMA, fp32 out.
// m97 structure: 128x128 tile, BK=32, 256 threads (4 waves, each 64x64 =
// 4x4 MFMA 16x16x32), global_load_lds width=16, 2-barrier K-loop.
// ---------------------------------------------------------------------------
__global__ __launch_bounds__(256) void had_gemm_kernel(
    const unsigned short* __restrict__ A,   // [M][K] bf16
    const unsigned short* __restrict__ B,   // [N][K] bf16 (W')
    const float* __restrict__ bias,         // [N]
    float* __restrict__ C,                  // [M][N] fp32
    int M, int N, int K)
{
    __shared__ __attribute__((aligned(16))) unsigned short As[128 * 32];
    __shared__ __attribute__((aligned(16))) unsigned short Bs[128 * 32];

    const int tid  = threadIdx.x;
    const int lane = tid & 63;
    const int wave = tid >> 6;
    const int m0 = blockIdx.y * 128;
    const int n0 = blockIdx.x * 128;
    const int wm = (wave & 1) * 64;   // wave's 64-row sub-tile
    const int wn = (wave >> 1) * 64;  // wave's 64-col sub-tile
    const int l16  = lane & 15;
    const int quad = lane >> 4;

    f32x4 acc[4][4] = {};

    // Staging: 8 chunks of 64 lanes x 16B cover each 128x32 bf16 tile.
    // LDS dest is wave-uniform base + lane*16 (global_load_lds semantics);
    // row-major [128][32] with no padding keeps lane order contiguous.
    const int u0 = (wave * 2 + 0) * 64 + lane;
    const int u1 = (wave * 2 + 1) * 64 + lane;
    const unsigned short* gA0 = A + (size_t)(m0 + (u0 >> 2)) * K + (u0 & 3) * 8;
    const unsigned short* gA1 = A + (size_t)(m0 + (u1 >> 2)) * K + (u1 & 3) * 8;
    const unsigned short* gB0 = B + (size_t)(n0 + (u0 >> 2)) * K + (u0 & 3) * 8;
    const unsigned short* gB1 = B + (size_t)(n0 + (u1 >> 2)) * K + (u1 & 3) * 8;
    unsigned short* lA0 = As + (wave * 2 + 0) * 512;  // wave-uniform bases
    unsigned short* lA1 = As + (wave * 2 + 1) * 512;
    unsigned short* lB0 = Bs + (wave * 2 + 0) * 512;
    unsigned short* lB1 = Bs + (wave * 2 + 1) * 512;

    // Fragment pointers: A-operand layout A[m=lane&15][k=quad*8+j] (m120),
    // 16B contiguous -> ds_read_b128.
    const unsigned short* pa = As + (wm + l16) * 32 + quad * 8;
    const unsigned short* pb = Bs + (wn + l16) * 32 + quad * 8;

    for (int k0 = 0; k0 < K; k0 += 32) {
        __builtin_amdgcn_global_load_lds(
            (__attribute__((address_space(1))) void*)(gA0 + k0),
            (__attribute__((address_space(3))) void*)lA0, 16, 0, 0);
        __builtin_amdgcn_global_load_lds(
            (__attribute__((address_space(1))) void*)(gA1 + k0),
            (__attribute__((address_space(3))) void*)lA1, 16, 0, 0);
        __builtin_amdgcn_global_load_lds(
            (__attribute__((address_space(1))) void*)(gB0 + k0),
            (__attribute__((address_space(3))) void*)lB0, 16, 0, 0);
        __builtin_amdgcn_global_load_lds(
            (__attribute__((address_space(1))) void*)(gB1 + k0),
            (__attribute__((address_space(3))) void*)lB1, 16, 0, 0);
        __syncthreads();  // drains vmcnt(0): staged data visible to all waves

        bf16x8 af[4], bfr[4];
        #pragma unroll
        for (int i = 0; i < 4; ++i) af[i]  = *(const bf16x8*)(pa + i * 512);
        #pragma unroll
        for (int j = 0; j < 4; ++j) bfr[j] = *(const bf16x8*)(pb + j * 512);
        #pragma unroll
        for (int i = 0; i < 4; ++i)
            #pragma unroll
            for (int j = 0; j < 4; ++j)
                acc[i][j] = __builtin_amdgcn_mfma_f32_16x16x32_bf16(
                    af[i], bfr[j], acc[i][j], 0, 0, 0);
        __syncthreads();  // all waves done reading LDS before next stage
    }

    // Epilogue: C/D layout col=lane&15, row=quad*4+reg (m89-verified).
    float bv[4];
    #pragma unroll
    for (int j = 0; j < 4; ++j) bv[j] = bias[n0 + wn + j * 16 + l16];

    #pragma unroll
    for (int i = 0; i < 4; ++i) {
        #pragma unroll
        for (int r = 0; r < 4; ++r) {
            int row = m0 + wm + i * 16 + quad * 4 + r;
            float* cp = C + (size_t)row * N + (n0 + wn + l16);
            #pragma unroll
            for (int j = 0; j < 4; ++j)
                cp[j * 16] = acc[i][j][r] + bv[j];
        }
    }
}

// ---------------------------------------------------------------------------
extern "C" void kernel_launch(void* const* d_in, const int* in_sizes, int n_in,
                              void* d_out, int out_size, void* d_ws, size_t ws_size,
                              hipStream_t stream) {
    const float* x = (const float*)d_in[0];  // [4,4096,2048] fp32
    const float* W = (const float*)d_in[1];  // [2048,2048]  fp32
    const float* b = (const float*)d_in[2];  // [2048]       fp32
    float* out = (float*)d_out;              // [4,4096,2048] fp32

    const int d = in_sizes[2];          // 2048
    const int M = in_sizes[0] / d;      // 16384
    const int N = d, K = d;

    // Workspace: A bf16 [M][K] (64 MB) + W' bf16 [N][K] (8 MB)
    unsigned short* A_ws  = (unsigned short*)d_ws;
    unsigned short* Bt_ws = A_ws + (size_t)M * K;

    int n4 = in_sizes[0] / 4;
    cast_x_kernel<<<(n4 + 255) / 256, 256, 0, stream>>>(
        (const float4*)x, (ushort4*)A_ws, n4);

    fwht_w_kernel<<<N, 256, 0, stream>>>(W, Bt_ws);

    dim3 grid(N / 128, M / 128);  // (16, 128)
    had_gemm_kernel<<<grid, 256, 0, stream>>>(A_ws, Bt_ws, b, out, M, N, K);
}